// Round 7
// baseline (411.321 us; speedup 1.0000x reference)
//
#include <hip/hip_runtime.h>
#include <cmath>

#define NC 192   // H*C
#define CC 64
#define DOUTK 16

typedef _Float16 f16x8 __attribute__((ext_vector_type(8)));
typedef _Float16 f16x4 __attribute__((ext_vector_type(4)));
typedef float f32x4 __attribute__((ext_vector_type(4)));

__device__ __forceinline__ float lrelu(float x) { return x > 0.f ? x : 0.2f * x; }

__device__ __forceinline__ float wred_sum(float v) {
#pragma unroll
  for (int off = 32; off; off >>= 1) v += __shfl_xor(v, off);
  return v;
}
__device__ __forceinline__ float wred_max(float v) {
#pragma unroll
  for (int off = 32; off; off >>= 1) v = fmaxf(v, __shfl_xor(v, off));
  return v;
}

// ---------------- CSR build (dst-sorted) ----------------
__global__ void k_hist(const int* __restrict__ dsts, int* __restrict__ deg, int E) {
  int e = blockIdx.x * 256 + threadIdx.x;
  if (e < E) atomicAdd(&deg[dsts[e]], 1);
}

__global__ void k_scan_block(const int* __restrict__ deg, int* __restrict__ rowptr,
                             int* __restrict__ bsum, int Nn) {
  __shared__ int tmp[256];
  int i = blockIdx.x * 256 + threadIdx.x;
  int v = (i < Nn) ? deg[i] : 0;
  tmp[threadIdx.x] = v;
  __syncthreads();
  for (int off = 1; off < 256; off <<= 1) {
    int t = (threadIdx.x >= off) ? tmp[threadIdx.x - off] : 0;
    __syncthreads();
    tmp[threadIdx.x] += t;
    __syncthreads();
  }
  if (i < Nn) rowptr[i] = tmp[threadIdx.x] - v;   // exclusive
  if (threadIdx.x == 255) bsum[blockIdx.x] = tmp[255];
}

__global__ void k_scan_bsum(int* __restrict__ bsum, int B) {
  __shared__ int tmp[256];
  int v = (threadIdx.x < B) ? bsum[threadIdx.x] : 0;
  tmp[threadIdx.x] = v;
  __syncthreads();
  for (int off = 1; off < 256; off <<= 1) {
    int t = (threadIdx.x >= off) ? tmp[threadIdx.x - off] : 0;
    __syncthreads();
    tmp[threadIdx.x] += t;
    __syncthreads();
  }
  if (threadIdx.x < B) bsum[threadIdx.x] = tmp[threadIdx.x] - v;  // exclusive
}

__global__ void k_add_off(int* __restrict__ rowptr, const int* __restrict__ bsum,
                          int* __restrict__ cursor, int Nn) {
  int i = blockIdx.x * 256 + threadIdx.x;
  if (i < Nn) {
    int r = rowptr[i] + bsum[blockIdx.x];
    rowptr[i] = r;
    cursor[i] = r;
  }
}

__global__ void k_scatter(const int* __restrict__ srcs, const int* __restrict__ dsts,
                          int* __restrict__ cursor, int* __restrict__ csr_src, int E) {
  int e = blockIdx.x * 256 + threadIdx.x;
  if (e < E) {
    int d = dsts[e];
    int p = atomicAdd(&cursor[d], 1);
    csr_src[p] = srcs[e];
  }
}

// ---------------- dtype conversion ----------------
__global__ void k_f2h(const float* __restrict__ in, _Float16* __restrict__ out, int n4) {
  int i = blockIdx.x * 256 + threadIdx.x;
  if (i < n4) {
    float4 v = *(const float4*)(in + (size_t)i * 4);
    f16x4 o;
    o[0] = (_Float16)v.x; o[1] = (_Float16)v.y;
    o[2] = (_Float16)v.z; o[3] = (_Float16)v.w;
    *(f16x4*)(out + (size_t)i * 4) = o;
  }
}

// W[K][192] fp32 -> WT[192][K] fp16
__global__ void k_wT(const float* __restrict__ W, _Float16* __restrict__ WT, int K) {
  int i = blockIdx.x * 256 + threadIdx.x;
  if (i < NC * K) {
    int c = i / K, k = i - c * K;
    WT[i] = (_Float16)W[(size_t)k * NC + c];
  }
}

// ---------------- LDS-staged MFMA GEMM + fused attention scores ----------------
template<int K>
__global__ __launch_bounds__(256) void k_gemm_mfma_att(
    const _Float16* __restrict__ A, const _Float16* __restrict__ WT,
    const float* __restrict__ att_src, const float* __restrict__ att_dst,
    _Float16* __restrict__ XW, float* __restrict__ asrc, float* __restrict__ adst,
    int M) {
  constexpr int KC = 32;
  constexpr int NCHUNK = K / KC;
  constexpr int AST = 40;                     // padded row stride (fp16)
  __shared__ _Float16 As[2][128][AST];
  __shared__ _Float16 Bs[2][192][AST];
  const int tid = threadIdx.x;
  const int lane = tid & 63, wv = tid >> 6;
  const int li = lane & 15, g = lane >> 4;
  const int row0 = blockIdx.x * 128;
  const int srow = tid >> 2, sseg = tid & 3;  // staging: 4 thr x 16B cover one 64B row-chunk

  f32x4 acc0[12], acc1[12];
#pragma unroll
  for (int t = 0; t < 12; ++t) {
    acc0[t] = (f32x4){0.f, 0.f, 0.f, 0.f};
    acc1[t] = (f32x4){0.f, 0.f, 0.f, 0.f};
  }

  const int ra0 = (row0 + srow      < M) ? row0 + srow      : M - 1;  // clamp tail
  const int ra1 = (row0 + 64 + srow < M) ? row0 + 64 + srow : M - 1;

  f16x8 a_st[2], b_st[3];
  auto stage_load = [&](int c) {
    const size_t ko = (size_t)c * KC + sseg * 8;
    a_st[0] = *(const f16x8*)(A + (size_t)ra0 * K + ko);
    a_st[1] = *(const f16x8*)(A + (size_t)ra1 * K + ko);
    b_st[0] = *(const f16x8*)(WT + (size_t)(srow)       * K + ko);
    b_st[1] = *(const f16x8*)(WT + (size_t)(64 + srow)  * K + ko);
    b_st[2] = *(const f16x8*)(WT + (size_t)(128 + srow) * K + ko);
  };
  auto stage_write = [&](int buf) {
    *(f16x8*)&As[buf][srow][sseg * 8]       = a_st[0];
    *(f16x8*)&As[buf][64 + srow][sseg * 8]  = a_st[1];
    *(f16x8*)&Bs[buf][srow][sseg * 8]       = b_st[0];
    *(f16x8*)&Bs[buf][64 + srow][sseg * 8]  = b_st[1];
    *(f16x8*)&Bs[buf][128 + srow][sseg * 8] = b_st[2];
  };

  stage_load(0);
  stage_write(0);
  __syncthreads();

  for (int c = 0; c < NCHUNK; ++c) {
    const int buf = c & 1;
    if (c + 1 < NCHUNK) stage_load(c + 1);
    f16x8 bf[12];
#pragma unroll
    for (int t = 0; t < 12; ++t) bf[t] = *(const f16x8*)&Bs[buf][t * 16 + li][g * 8];
    f16x8 af0 = *(const f16x8*)&As[buf][wv * 32 + li][g * 8];
    f16x8 af1 = *(const f16x8*)&As[buf][wv * 32 + 16 + li][g * 8];
#pragma unroll
    for (int t = 0; t < 12; ++t) {
      acc0[t] = __builtin_amdgcn_mfma_f32_16x16x32_f16(af0, bf[t], acc0[t], 0, 0, 0);
      acc1[t] = __builtin_amdgcn_mfma_f32_16x16x32_f16(af1, bf[t], acc1[t], 0, 0, 0);
    }
    if (c + 1 < NCHUNK) stage_write((c + 1) & 1);
    __syncthreads();
  }

  // epilogue: fp16 XW store + fused attention scores
  float avs[12], avd[12];
#pragma unroll
  for (int t = 0; t < 12; ++t) {
    avs[t] = att_src[t * 16 + li];
    avd[t] = att_dst[t * 16 + li];
  }
#pragma unroll
  for (int mt = 0; mt < 2; ++mt) {
    const f32x4* acc = mt ? acc1 : acc0;
    const int rbase = row0 + wv * 32 + mt * 16 + g * 4;
#pragma unroll
    for (int r = 0; r < 4; ++r) {
      const int row = rbase + r;
      const bool ok = row < M;
#pragma unroll
      for (int t = 0; t < 12; ++t)
        if (ok) XW[(size_t)row * NC + t * 16 + li] = (_Float16)acc[t][r];
#pragma unroll
      for (int h = 0; h < 3; ++h) {
        float s = acc[4*h][r]*avs[4*h] + acc[4*h+1][r]*avs[4*h+1] +
                  acc[4*h+2][r]*avs[4*h+2] + acc[4*h+3][r]*avs[4*h+3];
        float d = acc[4*h][r]*avd[4*h] + acc[4*h+1][r]*avd[4*h+1] +
                  acc[4*h+2][r]*avd[4*h+2] + acc[4*h+3][r]*avd[4*h+3];
#pragma unroll
        for (int off = 8; off; off >>= 1) {
          s += __shfl_xor(s, off);
          d += __shfl_xor(d, off);
        }
        if (ok && li == 0) {
          asrc[row * 3 + h] = s;
          adst[row * 3 + h] = d;
        }
      }
    }
  }
}

// ---------------- fused segment-softmax + aggregation, one wave per node ----------------
// Fast path (d<=64): normalized per-edge coefs (incl. /3 head-mean) + src ids go to a
// per-wave LDS table; gather = lane l<48 owns channels h*64+(l&15)*4 (h=l>>4), ONE f16x4
// load per edge per lane (whole 384B row in one wave-op), coef via conflict-free LDS
// broadcast, 4-edge unroll for MLP. Head-mean combine via 8 shfls, float4/f16x4 store.
template<bool RELU, typename OutT>
__global__ __launch_bounds__(256) void k_aggregate(
    const _Float16* __restrict__ xw, const float* __restrict__ asrc,
    const float* __restrict__ adst, const int* __restrict__ rowptr,
    const int* __restrict__ deg, const int* __restrict__ csr_src,
    const float* __restrict__ bias, OutT* __restrict__ out, int Nn) {
  __shared__ float coef_lds[4 * 3 * 72];
  __shared__ int src_lds[4 * 72];
  const int wid = threadIdx.x >> 6, lane = threadIdx.x & 63;
  const int n = blockIdx.x * 4 + wid;
  const bool valid = (n < Nn);

  int row = 0, d = 0;
  float ad0 = 0, ad1 = 0, ad2 = 0, sa0 = 0, sa1 = 0, sa2 = 0;
  bool fast = true;
  if (valid) {
    row = rowptr[n]; d = deg[n];
    float3 adv = *(const float3*)(adst + 3 * n);
    float3 asv = *(const float3*)(asrc + 3 * n);
    ad0 = adv.x; ad1 = adv.y; ad2 = adv.z;
    sa0 = lrelu(asv.x + ad0);   // self-loop alpha
    sa1 = lrelu(asv.y + ad1);
    sa2 = lrelu(asv.z + ad2);
    fast = (d <= 64);
  }

  if (valid && fast) {
    // ----- phase 1: per-edge alpha (lane e owns edge e), softmax, coef table -----
    int s = 0;
    float al0 = -INFINITY, al1 = -INFINITY, al2 = -INFINITY;
    if (lane < d) {
      s = csr_src[row + lane];
      float3 av = *(const float3*)(asrc + 3 * s);
      al0 = lrelu(av.x + ad0);
      al1 = lrelu(av.y + ad1);
      al2 = lrelu(av.z + ad2);
    }
    float m0 = fmaxf(wred_max(al0), sa0);
    float m1 = fmaxf(wred_max(al1), sa1);
    float m2 = fmaxf(wred_max(al2), sa2);
    float w0 = __expf(al0 - m0);   // inactive lanes: exp(-inf)=0
    float w1 = __expf(al1 - m1);
    float w2 = __expf(al2 - m2);
    float es0 = __expf(sa0 - m0), es1 = __expf(sa1 - m1), es2 = __expf(sa2 - m2);
    float S0 = wred_sum(w0) + es0 + 1e-16f;
    float S1 = wred_sum(w1) + es1 + 1e-16f;
    float S2 = wred_sum(w2) + es2 + 1e-16f;
    float r0 = 1.f / (3.f * S0), r1 = 1.f / (3.f * S1), r2 = 1.f / (3.f * S2);
    const int cb = wid * 3 * 72;
    if (lane < d) {
      coef_lds[cb + lane]       = w0 * r0;
      coef_lds[cb + 72 + lane]  = w1 * r1;
      coef_lds[cb + 144 + lane] = w2 * r2;
      src_lds[wid * 72 + lane] = s;
    }
    if (lane == 0) {   // self-loop as edge d
      coef_lds[cb + d]       = es0 * r0;
      coef_lds[cb + 72 + d]  = es1 * r1;
      coef_lds[cb + 144 + d] = es2 * r2;
      src_lds[wid * 72 + d] = n;
    }
  }
  __syncthreads();   // convergent for all waves

  if (!valid) return;

  if (fast) {
    // ----- phase 2: gather -----
    const int dd = d + 1;
    float a0 = 0.f, a1 = 0.f, a2 = 0.f, a3 = 0.f;
    const int h = (lane < 48) ? (lane >> 4) : 2;
    const int c4 = (lane & 15) * 4;
    const int coff = h * 64 + c4;
    const int cbh = (wid * 3 + h) * 72;
    if (lane < 48) {
      for (int e = 0; e < dd; e += 4) {
        int4 s4 = *(const int4*)&src_lds[wid * 72 + e];   // uniform broadcast
        {   // j = 0 (always valid)
          float c = coef_lds[cbh + e];
          f16x4 v = *(const f16x4*)(xw + (size_t)s4.x * NC + coff);
          a0 += c * (float)v[0]; a1 += c * (float)v[1];
          a2 += c * (float)v[2]; a3 += c * (float)v[3];
        }
        if (e + 1 < dd) {
          float c = coef_lds[cbh + e + 1];
          f16x4 v = *(const f16x4*)(xw + (size_t)s4.y * NC + coff);
          a0 += c * (float)v[0]; a1 += c * (float)v[1];
          a2 += c * (float)v[2]; a3 += c * (float)v[3];
        }
        if (e + 2 < dd) {
          float c = coef_lds[cbh + e + 2];
          f16x4 v = *(const f16x4*)(xw + (size_t)s4.z * NC + coff);
          a0 += c * (float)v[0]; a1 += c * (float)v[1];
          a2 += c * (float)v[2]; a3 += c * (float)v[3];
        }
        if (e + 3 < dd) {
          float c = coef_lds[cbh + e + 3];
          f16x4 v = *(const f16x4*)(xw + (size_t)s4.w * NC + coff);
          a0 += c * (float)v[0]; a1 += c * (float)v[1];
          a2 += c * (float)v[2]; a3 += c * (float)v[3];
        }
      }
    }
    // ----- phase 3: head-mean combine (coef already has /3 and /S) -----
    const int lb = lane & 15;
    float b0 = __shfl(a0, lb + 16), c0 = __shfl(a0, lb + 32);
    float b1 = __shfl(a1, lb + 16), c1 = __shfl(a1, lb + 32);
    float b2 = __shfl(a2, lb + 16), c2 = __shfl(a2, lb + 32);
    float b3 = __shfl(a3, lb + 16), c3 = __shfl(a3, lb + 32);
    if (lane < 16) {
      float4 bv = *(const float4*)&bias[lb * 4];
      float o0 = a0 + b0 + c0 + bv.x;
      float o1 = a1 + b1 + c1 + bv.y;
      float o2 = a2 + b2 + c2 + bv.z;
      float o3 = a3 + b3 + c3 + bv.w;
      if (RELU) {
        o0 = fmaxf(o0, 0.f); o1 = fmaxf(o1, 0.f);
        o2 = fmaxf(o2, 0.f); o3 = fmaxf(o3, 0.f);
      }
      if constexpr (sizeof(OutT) == 2) {
        f16x4 ov;
        ov[0] = (_Float16)o0; ov[1] = (_Float16)o1;
        ov[2] = (_Float16)o2; ov[3] = (_Float16)o3;
        *(f16x4*)(out + (size_t)n * CC + lb * 4) = ov;
      } else {
        float4 ov = make_float4(o0, o1, o2, o3);
        *(float4*)((float*)out + (size_t)n * CC + lb * 4) = ov;
      }
    }
  } else {
    // ----- slow path (d > 64): 3-pass, lane-strided (rare) -----
    float m0 = sa0, m1 = sa1, m2 = sa2;
    for (int e = lane; e < d; e += 64) {
      int s = csr_src[row + e];
      m0 = fmaxf(m0, lrelu(asrc[s * 3] + ad0));
      m1 = fmaxf(m1, lrelu(asrc[s * 3 + 1] + ad1));
      m2 = fmaxf(m2, lrelu(asrc[s * 3 + 2] + ad2));
    }
    m0 = wred_max(m0); m1 = wred_max(m1); m2 = wred_max(m2);
    float p0 = 0.f, p1 = 0.f, p2 = 0.f;
    for (int e = lane; e < d; e += 64) {
      int s = csr_src[row + e];
      p0 += __expf(lrelu(asrc[s * 3] + ad0) - m0);
      p1 += __expf(lrelu(asrc[s * 3 + 1] + ad1) - m1);
      p2 += __expf(lrelu(asrc[s * 3 + 2] + ad2) - m2);
    }
    float S0 = wred_sum(p0) + __expf(sa0 - m0) + 1e-16f;
    float S1 = wred_sum(p1) + __expf(sa1 - m1) + 1e-16f;
    float S2 = wred_sum(p2) + __expf(sa2 - m2) + 1e-16f;
    const _Float16* xrs = xw + (size_t)n * NC;
    float acc0 = __expf(sa0 - m0) * (float)xrs[lane];
    float acc1 = __expf(sa1 - m1) * (float)xrs[64 + lane];
    float acc2 = __expf(sa2 - m2) * (float)xrs[128 + lane];
    for (int e = 0; e < d; ++e) {
      int s = csr_src[row + e];
      float we0 = __expf(lrelu(asrc[s * 3] + ad0) - m0);
      float we1 = __expf(lrelu(asrc[s * 3 + 1] + ad1) - m1);
      float we2 = __expf(lrelu(asrc[s * 3 + 2] + ad2) - m2);
      const _Float16* xr = xw + (size_t)s * NC;
      acc0 += we0 * (float)xr[lane];
      acc1 += we1 * (float)xr[64 + lane];
      acc2 += we2 * (float)xr[128 + lane];
    }
    float o = (acc0 / S0 + acc1 / S1 + acc2 / S2) * (1.f / 3.f) + bias[lane];
    out[(size_t)n * CC + lane] = (OutT)(RELU ? fmaxf(o, 0.f) : o);
  }
}

// ---------------- final linear: logit[N,16] = h[N,64] @ Wl[64,16] + bl ----------------
__global__ void k_logit(const float* __restrict__ h, const float* __restrict__ Wl,
                        const float* __restrict__ bl, float* __restrict__ out, int Nn) {
  __shared__ float wl_s[CC * DOUTK];
  __shared__ float hrow[4][CC];
  int tid = threadIdx.x;
  for (int i = tid; i < CC * DOUTK; i += 256) wl_s[i] = Wl[i];
  int wid = tid >> 6, lane = tid & 63;
  int n = blockIdx.x * 4 + wid;
  if (n < Nn) hrow[wid][lane] = h[(size_t)n * CC + lane];
  __syncthreads();
  if (n < Nn && lane < DOUTK) {
    float acc = bl[lane];
#pragma unroll
    for (int c = 0; c < CC; ++c) acc += hrow[wid][c] * wl_s[c * DOUTK + lane];
    out[(size_t)n * DOUTK + lane] = acc;
  }
}

extern "C" void kernel_launch(void* const* d_in, const int* in_sizes, int n_in,
                              void* d_out, int out_size, void* d_ws, size_t ws_size,
                              hipStream_t stream) {
  const float* x   = (const float*)d_in[0];
  const float* W1  = (const float*)d_in[1];
  const float* as1 = (const float*)d_in[2];
  const float* ad1 = (const float*)d_in[3];
  const float* b1  = (const float*)d_in[4];
  const float* W2  = (const float*)d_in[5];
  const float* as2 = (const float*)d_in[6];
  const float* ad2 = (const float*)d_in[7];
  const float* b2  = (const float*)d_in[8];
  const float* Wl  = (const float*)d_in[9];
  const float* bl  = (const float*)d_in[10];
  const int* edges = (const int*)d_in[11];

  const int Nn = in_sizes[0] / 256;   // 50000
  const int E  = in_sizes[11] / 2;    // 800000
  const int* srcs = edges;
  const int* dsts = edges + E;

  float* out_logit = (float*)d_out;                       // [N,16]
  float* out_h     = (float*)d_out + (size_t)Nn * DOUTK;  // [N,64]

  char* p = (char*)d_ws;
  auto alloc = [&](size_t bytes) {
    char* r = p;
    p += (bytes + 255) & ~(size_t)255;
    return r;
  };
  _Float16* xw   = (_Float16*)alloc((size_t)Nn * NC * 2);   // fp16 XW (gather source)
  _Float16* xh   = (_Float16*)alloc((size_t)Nn * 256 * 2);  // fp16 x
  _Float16* h1h  = (_Float16*)alloc((size_t)Nn * CC * 2);   // fp16 layer-1 output
  _Float16* wT1  = (_Float16*)alloc((size_t)NC * 256 * 2);
  _Float16* wT2  = (_Float16*)alloc((size_t)NC * CC * 2);
  float* asrc    = (float*)alloc((size_t)Nn * 3 * 4);
  float* adst    = (float*)alloc((size_t)Nn * 3 * 4);
  int* deg       = (int*)alloc((size_t)Nn * 4);
  int* rowptr    = (int*)alloc((size_t)Nn * 4);
  int* cursor    = (int*)alloc((size_t)Nn * 4);
  int* bsum      = (int*)alloc(256 * 4);
  int* csr_src   = (int*)alloc((size_t)E * 4);

  const int nB = (Nn + 255) / 256;   // 196 (<=256 required by k_scan_bsum)
  const int eB = (E + 255) / 256;
  const int gB = (Nn + 127) / 128;
  const int aB = (Nn + 3) / 4;

  // CSR build (ws is re-poisoned every call -> rebuild everything)
  hipMemsetAsync(deg, 0, (size_t)Nn * 4, stream);
  k_hist<<<eB, 256, 0, stream>>>(dsts, deg, E);
  k_scan_block<<<nB, 256, 0, stream>>>(deg, rowptr, bsum, Nn);
  k_scan_bsum<<<1, 256, 0, stream>>>(bsum, nB);
  k_add_off<<<nB, 256, 0, stream>>>(rowptr, bsum, cursor, Nn);
  k_scatter<<<eB, 256, 0, stream>>>(srcs, dsts, cursor, csr_src, E);

  // dtype prep
  const int nx4 = Nn * 256 / 4;
  k_f2h<<<(nx4 + 255) / 256, 256, 0, stream>>>(x, xh, nx4);
  k_wT<<<(NC * 256 + 255) / 256, 256, 0, stream>>>(W1, wT1, 256);
  k_wT<<<(NC * CC + 255) / 256, 256, 0, stream>>>(W2, wT2, CC);

  // layer 1
  k_gemm_mfma_att<256><<<gB, 256, 0, stream>>>(xh, wT1, as1, ad1, xw, asrc, adst, Nn);
  k_aggregate<true, _Float16><<<aB, 256, 0, stream>>>(xw, asrc, adst, rowptr, deg,
                                                      csr_src, b1, h1h, Nn);

  // layer 2
  k_gemm_mfma_att<64><<<gB, 256, 0, stream>>>(h1h, wT2, as2, ad2, xw, asrc, adst, Nn);
  k_aggregate<false, float><<<aB, 256, 0, stream>>>(xw, asrc, adst, rowptr, deg,
                                                    csr_src, b2, out_h, Nn);

  // final linear
  k_logit<<<aB, 256, 0, stream>>>(out_h, Wl, bl, out_logit, Nn);
}

// Round 8
// 385.832 us; speedup vs baseline: 1.0661x; 1.0661x over previous
//
#include <hip/hip_runtime.h>
#include <cmath>

#define NC 192   // H*C
#define CC 64
#define DOUTK 16

typedef _Float16 f16x8 __attribute__((ext_vector_type(8)));
typedef _Float16 f16x4 __attribute__((ext_vector_type(4)));
typedef float f32x4 __attribute__((ext_vector_type(4)));

__device__ __forceinline__ float lrelu(float x) { return x > 0.f ? x : 0.2f * x; }

__device__ __forceinline__ float wred_sum(float v) {
#pragma unroll
  for (int off = 32; off; off >>= 1) v += __shfl_xor(v, off);
  return v;
}
__device__ __forceinline__ float wred_max(float v) {
#pragma unroll
  for (int off = 32; off; off >>= 1) v = fmaxf(v, __shfl_xor(v, off));
  return v;
}
// 32-lane half-wave reductions (xor masks <32 keep halves separate)
__device__ __forceinline__ float h32_sum(float v) {
#pragma unroll
  for (int off = 16; off; off >>= 1) v += __shfl_xor(v, off);
  return v;
}
__device__ __forceinline__ float h32_max(float v) {
#pragma unroll
  for (int off = 16; off; off >>= 1) v = fmaxf(v, __shfl_xor(v, off));
  return v;
}

// ---------------- CSR build (dst-sorted) ----------------
__global__ void k_hist(const int* __restrict__ dsts, int* __restrict__ deg, int E) {
  int e = blockIdx.x * 256 + threadIdx.x;
  if (e < E) atomicAdd(&deg[dsts[e]], 1);
}

__global__ void k_scan_block(const int* __restrict__ deg, int* __restrict__ rowptr,
                             int* __restrict__ bsum, int Nn) {
  __shared__ int tmp[256];
  int i = blockIdx.x * 256 + threadIdx.x;
  int v = (i < Nn) ? deg[i] : 0;
  tmp[threadIdx.x] = v;
  __syncthreads();
  for (int off = 1; off < 256; off <<= 1) {
    int t = (threadIdx.x >= off) ? tmp[threadIdx.x - off] : 0;
    __syncthreads();
    tmp[threadIdx.x] += t;
    __syncthreads();
  }
  if (i < Nn) rowptr[i] = tmp[threadIdx.x] - v;   // exclusive
  if (threadIdx.x == 255) bsum[blockIdx.x] = tmp[255];
}

__global__ void k_scan_bsum(int* __restrict__ bsum, int B) {
  __shared__ int tmp[256];
  int v = (threadIdx.x < B) ? bsum[threadIdx.x] : 0;
  tmp[threadIdx.x] = v;
  __syncthreads();
  for (int off = 1; off < 256; off <<= 1) {
    int t = (threadIdx.x >= off) ? tmp[threadIdx.x - off] : 0;
    __syncthreads();
    tmp[threadIdx.x] += t;
    __syncthreads();
  }
  if (threadIdx.x < B) bsum[threadIdx.x] = tmp[threadIdx.x] - v;  // exclusive
}

__global__ void k_add_off(int* __restrict__ rowptr, const int* __restrict__ bsum,
                          int* __restrict__ cursor, int Nn) {
  int i = blockIdx.x * 256 + threadIdx.x;
  if (i < Nn) {
    int r = rowptr[i] + bsum[blockIdx.x];
    rowptr[i] = r;
    cursor[i] = r;
  }
}

__global__ void k_scatter(const int* __restrict__ srcs, const int* __restrict__ dsts,
                          int* __restrict__ cursor, int* __restrict__ csr_src, int E) {
  int e = blockIdx.x * 256 + threadIdx.x;
  if (e < E) {
    int d = dsts[e];
    int p = atomicAdd(&cursor[d], 1);
    csr_src[p] = srcs[e];
  }
}

// ---------------- dtype conversion ----------------
__global__ void k_f2h(const float* __restrict__ in, _Float16* __restrict__ out, int n4) {
  int i = blockIdx.x * 256 + threadIdx.x;
  if (i < n4) {
    float4 v = *(const float4*)(in + (size_t)i * 4);
    f16x4 o;
    o[0] = (_Float16)v.x; o[1] = (_Float16)v.y;
    o[2] = (_Float16)v.z; o[3] = (_Float16)v.w;
    *(f16x4*)(out + (size_t)i * 4) = o;
  }
}

// W[K][192] fp32 -> WT[192][K] fp16
__global__ void k_wT(const float* __restrict__ W, _Float16* __restrict__ WT, int K) {
  int i = blockIdx.x * 256 + threadIdx.x;
  if (i < NC * K) {
    int c = i / K, k = i - c * K;
    WT[i] = (_Float16)W[(size_t)k * NC + c];
  }
}

// ---------------- LDS-staged MFMA GEMM + fused attention scores ----------------
template<int K>
__global__ __launch_bounds__(256) void k_gemm_mfma_att(
    const _Float16* __restrict__ A, const _Float16* __restrict__ WT,
    const float* __restrict__ att_src, const float* __restrict__ att_dst,
    _Float16* __restrict__ XW, float* __restrict__ asrc, float* __restrict__ adst,
    int M) {
  constexpr int KC = 32;
  constexpr int NCHUNK = K / KC;
  constexpr int AST = 40;                     // padded row stride (fp16)
  __shared__ _Float16 As[2][128][AST];
  __shared__ _Float16 Bs[2][192][AST];
  const int tid = threadIdx.x;
  const int lane = tid & 63, wv = tid >> 6;
  const int li = lane & 15, g = lane >> 4;
  const int row0 = blockIdx.x * 128;
  const int srow = tid >> 2, sseg = tid & 3;  // staging: 4 thr x 16B cover one 64B row-chunk

  f32x4 acc0[12], acc1[12];
#pragma unroll
  for (int t = 0; t < 12; ++t) {
    acc0[t] = (f32x4){0.f, 0.f, 0.f, 0.f};
    acc1[t] = (f32x4){0.f, 0.f, 0.f, 0.f};
  }

  const int ra0 = (row0 + srow      < M) ? row0 + srow      : M - 1;  // clamp tail
  const int ra1 = (row0 + 64 + srow < M) ? row0 + 64 + srow : M - 1;

  f16x8 a_st[2], b_st[3];
  auto stage_load = [&](int c) {
    const size_t ko = (size_t)c * KC + sseg * 8;
    a_st[0] = *(const f16x8*)(A + (size_t)ra0 * K + ko);
    a_st[1] = *(const f16x8*)(A + (size_t)ra1 * K + ko);
    b_st[0] = *(const f16x8*)(WT + (size_t)(srow)       * K + ko);
    b_st[1] = *(const f16x8*)(WT + (size_t)(64 + srow)  * K + ko);
    b_st[2] = *(const f16x8*)(WT + (size_t)(128 + srow) * K + ko);
  };
  auto stage_write = [&](int buf) {
    *(f16x8*)&As[buf][srow][sseg * 8]       = a_st[0];
    *(f16x8*)&As[buf][64 + srow][sseg * 8]  = a_st[1];
    *(f16x8*)&Bs[buf][srow][sseg * 8]       = b_st[0];
    *(f16x8*)&Bs[buf][64 + srow][sseg * 8]  = b_st[1];
    *(f16x8*)&Bs[buf][128 + srow][sseg * 8] = b_st[2];
  };

  stage_load(0);
  stage_write(0);
  __syncthreads();

  for (int c = 0; c < NCHUNK; ++c) {
    const int buf = c & 1;
    if (c + 1 < NCHUNK) stage_load(c + 1);
    f16x8 bf[12];
#pragma unroll
    for (int t = 0; t < 12; ++t) bf[t] = *(const f16x8*)&Bs[buf][t * 16 + li][g * 8];
    f16x8 af0 = *(const f16x8*)&As[buf][wv * 32 + li][g * 8];
    f16x8 af1 = *(const f16x8*)&As[buf][wv * 32 + 16 + li][g * 8];
#pragma unroll
    for (int t = 0; t < 12; ++t) {
      acc0[t] = __builtin_amdgcn_mfma_f32_16x16x32_f16(af0, bf[t], acc0[t], 0, 0, 0);
      acc1[t] = __builtin_amdgcn_mfma_f32_16x16x32_f16(af1, bf[t], acc1[t], 0, 0, 0);
    }
    if (c + 1 < NCHUNK) stage_write((c + 1) & 1);
    __syncthreads();
  }

  // epilogue: fp16 XW store + fused attention scores
  float avs[12], avd[12];
#pragma unroll
  for (int t = 0; t < 12; ++t) {
    avs[t] = att_src[t * 16 + li];
    avd[t] = att_dst[t * 16 + li];
  }
#pragma unroll
  for (int mt = 0; mt < 2; ++mt) {
    const f32x4* acc = mt ? acc1 : acc0;
    const int rbase = row0 + wv * 32 + mt * 16 + g * 4;
#pragma unroll
    for (int r = 0; r < 4; ++r) {
      const int row = rbase + r;
      const bool ok = row < M;
#pragma unroll
      for (int t = 0; t < 12; ++t)
        if (ok) XW[(size_t)row * NC + t * 16 + li] = (_Float16)acc[t][r];
#pragma unroll
      for (int h = 0; h < 3; ++h) {
        float s = acc[4*h][r]*avs[4*h] + acc[4*h+1][r]*avs[4*h+1] +
                  acc[4*h+2][r]*avs[4*h+2] + acc[4*h+3][r]*avs[4*h+3];
        float d = acc[4*h][r]*avd[4*h] + acc[4*h+1][r]*avd[4*h+1] +
                  acc[4*h+2][r]*avd[4*h+2] + acc[4*h+3][r]*avd[4*h+3];
#pragma unroll
        for (int off = 8; off; off >>= 1) {
          s += __shfl_xor(s, off);
          d += __shfl_xor(d, off);
        }
        if (ok && li == 0) {
          asrc[row * 3 + h] = s;
          adst[row * 3 + h] = d;
        }
      }
    }
  }
}

// ---------------- fused segment-softmax + aggregation, TWO nodes per wave ----------------
// Pair path (both d<=32, ~99.9% of nodes): phase 1 computes both nodes' softmax in
// 32-lane halves; coef (incl /3 /S) + src tables zero-PADDED to mult-of-4 -> guard-free
// gather loop issues 8 independent f16x4 loads (4 edges x 2 nodes) per iter = 2x MLP.
// Tables are wave-private: NO __syncthreads (wave-synchronous LDS).
template<bool RELU, typename OutT>
__global__ __launch_bounds__(256) void k_aggregate(
    const _Float16* __restrict__ xw, const float* __restrict__ asrc,
    const float* __restrict__ adst, const int* __restrict__ rowptr,
    const int* __restrict__ deg, const int* __restrict__ csr_src,
    const float* __restrict__ bias, OutT* __restrict__ out, int Nn) {
  __shared__ float coef_lds[4][2][3][40];
  __shared__ int   src_lds[4][2][40];
  const int wid = threadIdx.x >> 6, lane = threadIdx.x & 63;
  const int hf = lane >> 5, lh = lane & 31;
  const int nbase = blockIdx.x * 8 + wid * 2;
  const int n0 = nbase + hf;              // this half's node (phase 1)
  const bool v0 = (n0 < Nn);

  int row = 0, d = 0;
  float ad0 = 0, ad1 = 0, ad2 = 0, sa0 = 0, sa1 = 0, sa2 = 0;
  if (v0) {
    row = rowptr[n0]; d = deg[n0];
    float3 adv = *(const float3*)(adst + 3 * n0);
    float3 asv = *(const float3*)(asrc + 3 * n0);
    ad0 = adv.x; ad1 = adv.y; ad2 = adv.z;
    sa0 = lrelu(asv.x + ad0);
    sa1 = lrelu(asv.y + ad1);
    sa2 = lrelu(asv.z + ad2);
  }

  if (__all(d <= 32)) {
    // ----- phase 1 (paired): lane lh of each half owns edge lh of its node -----
    int s = 0;
    float al0 = -INFINITY, al1 = -INFINITY, al2 = -INFINITY;
    const bool haveE = v0 && (lh < d);
    if (haveE) {
      s = csr_src[row + lh];
      float3 av = *(const float3*)(asrc + 3 * s);
      al0 = lrelu(av.x + ad0);
      al1 = lrelu(av.y + ad1);
      al2 = lrelu(av.z + ad2);
    }
    float m0 = fmaxf(h32_max(al0), sa0);
    float m1 = fmaxf(h32_max(al1), sa1);
    float m2 = fmaxf(h32_max(al2), sa2);
    float w0 = __expf(al0 - m0);   // 0 on non-edge lanes
    float w1 = __expf(al1 - m1);
    float w2 = __expf(al2 - m2);
    float es0 = __expf(sa0 - m0), es1 = __expf(sa1 - m1), es2 = __expf(sa2 - m2);
    float S0 = h32_sum(w0) + es0 + 1e-16f;
    float S1 = h32_sum(w1) + es1 + 1e-16f;
    float S2 = h32_sum(w2) + es2 + 1e-16f;
    float r0 = 1.f / (3.f * S0), r1 = 1.f / (3.f * S1), r2 = 1.f / (3.f * S2);

    // zero-init table (entries lh and 32+lh), then overwrite self + edges.
    // Same-wave program order makes the overwrite safe without a barrier.
    const int nsafe = v0 ? n0 : 0;
    coef_lds[wid][hf][0][lh] = 0.f;
    coef_lds[wid][hf][1][lh] = 0.f;
    coef_lds[wid][hf][2][lh] = 0.f;
    src_lds[wid][hf][lh] = nsafe;
    if (lh < 8) {
      coef_lds[wid][hf][0][32 + lh] = 0.f;
      coef_lds[wid][hf][1][32 + lh] = 0.f;
      coef_lds[wid][hf][2][32 + lh] = 0.f;
      src_lds[wid][hf][32 + lh] = nsafe;
    }
    if (v0 && lh == 0) {               // self-loop entry at index d
      coef_lds[wid][hf][0][d] = es0 * r0;
      coef_lds[wid][hf][1][d] = es1 * r1;
      coef_lds[wid][hf][2][d] = es2 * r2;
      src_lds[wid][hf][d] = n0;
    }
    if (haveE) {
      coef_lds[wid][hf][0][lh] = w0 * r0;
      coef_lds[wid][hf][1][lh] = w1 * r1;
      coef_lds[wid][hf][2][lh] = w2 * r2;
      src_lds[wid][hf][lh] = s;
    }

    const int dA = __shfl(d, 0), dB = __shfl(d, 32);
    const int ddm = (((dA > dB ? dA : dB) + 1) + 3) & ~3;   // common padded length

    // ----- phase 2: guard-free gather, 8 loads in flight per iter -----
    float aA0 = 0, aA1 = 0, aA2 = 0, aA3 = 0;
    float aB0 = 0, aB1 = 0, aB2 = 0, aB3 = 0;
    const int h = (lane < 48) ? (lane >> 4) : 2;
    const int coff = h * 64 + (lane & 15) * 4;
    if (lane < 48) {
      const float* cA = &coef_lds[wid][0][h][0];
      const float* cB = &coef_lds[wid][1][h][0];
      const int* sAp = &src_lds[wid][0][0];
      const int* sBp = &src_lds[wid][1][0];
      for (int e = 0; e < ddm; e += 4) {
        int4 s4a = *(const int4*)&sAp[e];
        int4 s4b = *(const int4*)&sBp[e];
        f16x4 va0 = *(const f16x4*)(xw + (size_t)s4a.x * NC + coff);
        f16x4 va1 = *(const f16x4*)(xw + (size_t)s4a.y * NC + coff);
        f16x4 va2 = *(const f16x4*)(xw + (size_t)s4a.z * NC + coff);
        f16x4 va3 = *(const f16x4*)(xw + (size_t)s4a.w * NC + coff);
        f16x4 vb0 = *(const f16x4*)(xw + (size_t)s4b.x * NC + coff);
        f16x4 vb1 = *(const f16x4*)(xw + (size_t)s4b.y * NC + coff);
        f16x4 vb2 = *(const f16x4*)(xw + (size_t)s4b.z * NC + coff);
        f16x4 vb3 = *(const f16x4*)(xw + (size_t)s4b.w * NC + coff);
        float ca0 = cA[e], ca1 = cA[e + 1], ca2 = cA[e + 2], ca3 = cA[e + 3];
        float cb0 = cB[e], cb1 = cB[e + 1], cb2 = cB[e + 2], cb3 = cB[e + 3];
        aA0 += ca0 * (float)va0[0]; aA1 += ca0 * (float)va0[1];
        aA2 += ca0 * (float)va0[2]; aA3 += ca0 * (float)va0[3];
        aA0 += ca1 * (float)va1[0]; aA1 += ca1 * (float)va1[1];
        aA2 += ca1 * (float)va1[2]; aA3 += ca1 * (float)va1[3];
        aA0 += ca2 * (float)va2[0]; aA1 += ca2 * (float)va2[1];
        aA2 += ca2 * (float)va2[2]; aA3 += ca2 * (float)va2[3];
        aA0 += ca3 * (float)va3[0]; aA1 += ca3 * (float)va3[1];
        aA2 += ca3 * (float)va3[2]; aA3 += ca3 * (float)va3[3];
        aB0 += cb0 * (float)vb0[0]; aB1 += cb0 * (float)vb0[1];
        aB2 += cb0 * (float)vb0[2]; aB3 += cb0 * (float)vb0[3];
        aB0 += cb1 * (float)vb1[0]; aB1 += cb1 * (float)vb1[1];
        aB2 += cb1 * (float)vb1[2]; aB3 += cb1 * (float)vb1[3];
        aB0 += cb2 * (float)vb2[0]; aB1 += cb2 * (float)vb2[1];
        aB2 += cb2 * (float)vb2[2]; aB3 += cb2 * (float)vb2[3];
        aB0 += cb3 * (float)vb3[0]; aB1 += cb3 * (float)vb3[1];
        aB2 += cb3 * (float)vb3[2]; aB3 += cb3 * (float)vb3[3];
      }
    }

    // ----- phase 3: head-mean combine (coef already has /3 and /S) -----
    const int lb = lane & 15;
#define FOLD3(a) ((a) + __shfl((a), lb + 16) + __shfl((a), lb + 32))
    float oA0 = FOLD3(aA0), oA1 = FOLD3(aA1), oA2 = FOLD3(aA2), oA3 = FOLD3(aA3);
    float oB0 = FOLD3(aB0), oB1 = FOLD3(aB1), oB2 = FOLD3(aB2), oB3 = FOLD3(aB3);
#undef FOLD3
    if (lane < 16) {
      float4 bv = *(const float4*)&bias[lb * 4];
      if (nbase < Nn) {
        float p0 = oA0 + bv.x, p1 = oA1 + bv.y, p2 = oA2 + bv.z, p3 = oA3 + bv.w;
        if (RELU) {
          p0 = fmaxf(p0, 0.f); p1 = fmaxf(p1, 0.f);
          p2 = fmaxf(p2, 0.f); p3 = fmaxf(p3, 0.f);
        }
        if constexpr (sizeof(OutT) == 2) {
          f16x4 ov; ov[0] = (_Float16)p0; ov[1] = (_Float16)p1;
          ov[2] = (_Float16)p2; ov[3] = (_Float16)p3;
          *(f16x4*)(out + (size_t)nbase * CC + lb * 4) = ov;
        } else {
          *(float4*)((float*)out + (size_t)nbase * CC + lb * 4) =
              make_float4(p0, p1, p2, p3);
        }
      }
      if (nbase + 1 < Nn) {
        float p0 = oB0 + bv.x, p1 = oB1 + bv.y, p2 = oB2 + bv.z, p3 = oB3 + bv.w;
        if (RELU) {
          p0 = fmaxf(p0, 0.f); p1 = fmaxf(p1, 0.f);
          p2 = fmaxf(p2, 0.f); p3 = fmaxf(p3, 0.f);
        }
        if constexpr (sizeof(OutT) == 2) {
          f16x4 ov; ov[0] = (_Float16)p0; ov[1] = (_Float16)p1;
          ov[2] = (_Float16)p2; ov[3] = (_Float16)p3;
          *(f16x4*)(out + (size_t)(nbase + 1) * CC + lb * 4) = ov;
        } else {
          *(float4*)((float*)out + (size_t)(nbase + 1) * CC + lb * 4) =
              make_float4(p0, p1, p2, p3);
        }
      }
    }
  } else {
    // ----- cold path (any d>32 in the pair): generic 3-pass per node, whole wave -----
    for (int k2 = 0; k2 < 2; ++k2) {
      const int nx = nbase + k2;
      if (nx >= Nn) continue;
      const int rowx = rowptr[nx], dx = deg[nx];
      float3 adv = *(const float3*)(adst + 3 * nx);
      float3 asv = *(const float3*)(asrc + 3 * nx);
      const float bd0 = adv.x, bd1 = adv.y, bd2 = adv.z;
      const float ss0 = lrelu(asv.x + bd0);
      const float ss1 = lrelu(asv.y + bd1);
      const float ss2 = lrelu(asv.z + bd2);
      float m0 = ss0, m1 = ss1, m2 = ss2;
      for (int e = lane; e < dx; e += 64) {
        int s = csr_src[rowx + e];
        m0 = fmaxf(m0, lrelu(asrc[s * 3] + bd0));
        m1 = fmaxf(m1, lrelu(asrc[s * 3 + 1] + bd1));
        m2 = fmaxf(m2, lrelu(asrc[s * 3 + 2] + bd2));
      }
      m0 = wred_max(m0); m1 = wred_max(m1); m2 = wred_max(m2);
      float p0 = 0.f, p1 = 0.f, p2 = 0.f;
      for (int e = lane; e < dx; e += 64) {
        int s = csr_src[rowx + e];
        p0 += __expf(lrelu(asrc[s * 3] + bd0) - m0);
        p1 += __expf(lrelu(asrc[s * 3 + 1] + bd1) - m1);
        p2 += __expf(lrelu(asrc[s * 3 + 2] + bd2) - m2);
      }
      float S0 = wred_sum(p0) + __expf(ss0 - m0) + 1e-16f;
      float S1 = wred_sum(p1) + __expf(ss1 - m1) + 1e-16f;
      float S2 = wred_sum(p2) + __expf(ss2 - m2) + 1e-16f;
      const _Float16* xrs = xw + (size_t)nx * NC;
      float acc0 = __expf(ss0 - m0) * (float)xrs[lane];
      float acc1 = __expf(ss1 - m1) * (float)xrs[64 + lane];
      float acc2 = __expf(ss2 - m2) * (float)xrs[128 + lane];
      for (int e = 0; e < dx; ++e) {
        int s = csr_src[rowx + e];
        float we0 = __expf(lrelu(asrc[s * 3] + bd0) - m0);
        float we1 = __expf(lrelu(asrc[s * 3 + 1] + bd1) - m1);
        float we2 = __expf(lrelu(asrc[s * 3 + 2] + bd2) - m2);
        const _Float16* xr = xw + (size_t)s * NC;
        acc0 += we0 * (float)xr[lane];
        acc1 += we1 * (float)xr[64 + lane];
        acc2 += we2 * (float)xr[128 + lane];
      }
      float o = (acc0 / S0 + acc1 / S1 + acc2 / S2) * (1.f / 3.f) + bias[lane];
      out[(size_t)nx * CC + lane] = (OutT)(RELU ? fmaxf(o, 0.f) : o);
    }
  }
}

// ---------------- final linear: logit[N,16] = h[N,64] @ Wl[64,16] + bl ----------------
__global__ void k_logit(const float* __restrict__ h, const float* __restrict__ Wl,
                        const float* __restrict__ bl, float* __restrict__ out, int Nn) {
  __shared__ float wl_s[CC * DOUTK];
  __shared__ float hrow[4][CC];
  int tid = threadIdx.x;
  for (int i = tid; i < CC * DOUTK; i += 256) wl_s[i] = Wl[i];
  int wid = tid >> 6, lane = tid & 63;
  int n = blockIdx.x * 4 + wid;
  if (n < Nn) hrow[wid][lane] = h[(size_t)n * CC + lane];
  __syncthreads();
  if (n < Nn && lane < DOUTK) {
    float acc = bl[lane];
#pragma unroll
    for (int c = 0; c < CC; ++c) acc += hrow[wid][c] * wl_s[c * DOUTK + lane];
    out[(size_t)n * DOUTK + lane] = acc;
  }
}

extern "C" void kernel_launch(void* const* d_in, const int* in_sizes, int n_in,
                              void* d_out, int out_size, void* d_ws, size_t ws_size,
                              hipStream_t stream) {
  const float* x   = (const float*)d_in[0];
  const float* W1  = (const float*)d_in[1];
  const float* as1 = (const float*)d_in[2];
  const float* ad1 = (const float*)d_in[3];
  const float* b1  = (const float*)d_in[4];
  const float* W2  = (const float*)d_in[5];
  const float* as2 = (const float*)d_in[6];
  const float* ad2 = (const float*)d_in[7];
  const float* b2  = (const float*)d_in[8];
  const float* Wl  = (const float*)d_in[9];
  const float* bl  = (const float*)d_in[10];
  const int* edges = (const int*)d_in[11];

  const int Nn = in_sizes[0] / 256;   // 50000
  const int E  = in_sizes[11] / 2;    // 800000
  const int* srcs = edges;
  const int* dsts = edges + E;

  float* out_logit = (float*)d_out;                       // [N,16]
  float* out_h     = (float*)d_out + (size_t)Nn * DOUTK;  // [N,64]

  char* p = (char*)d_ws;
  auto alloc = [&](size_t bytes) {
    char* r = p;
    p += (bytes + 255) & ~(size_t)255;
    return r;
  };
  _Float16* xw   = (_Float16*)alloc((size_t)Nn * NC * 2);   // fp16 XW (gather source)
  _Float16* xh   = (_Float16*)alloc((size_t)Nn * 256 * 2);  // fp16 x
  _Float16* h1h  = (_Float16*)alloc((size_t)Nn * CC * 2);   // fp16 layer-1 output
  _Float16* wT1  = (_Float16*)alloc((size_t)NC * 256 * 2);
  _Float16* wT2  = (_Float16*)alloc((size_t)NC * CC * 2);
  float* asrc    = (float*)alloc((size_t)Nn * 3 * 4);
  float* adst    = (float*)alloc((size_t)Nn * 3 * 4);
  int* deg       = (int*)alloc((size_t)Nn * 4);
  int* rowptr    = (int*)alloc((size_t)Nn * 4);
  int* cursor    = (int*)alloc((size_t)Nn * 4);
  int* bsum      = (int*)alloc(256 * 4);
  int* csr_src   = (int*)alloc((size_t)E * 4);

  const int nB = (Nn + 255) / 256;   // 196 (<=256 required by k_scan_bsum)
  const int eB = (E + 255) / 256;
  const int gB = (Nn + 127) / 128;
  const int aB = (Nn + 7) / 8;
  const int lB = (Nn + 3) / 4;

  // CSR build (ws is re-poisoned every call -> rebuild everything)
  hipMemsetAsync(deg, 0, (size_t)Nn * 4, stream);
  k_hist<<<eB, 256, 0, stream>>>(dsts, deg, E);
  k_scan_block<<<nB, 256, 0, stream>>>(deg, rowptr, bsum, Nn);
  k_scan_bsum<<<1, 256, 0, stream>>>(bsum, nB);
  k_add_off<<<nB, 256, 0, stream>>>(rowptr, bsum, cursor, Nn);
  k_scatter<<<eB, 256, 0, stream>>>(srcs, dsts, cursor, csr_src, E);

  // dtype prep
  const int nx4 = Nn * 256 / 4;
  k_f2h<<<(nx4 + 255) / 256, 256, 0, stream>>>(x, xh, nx4);
  k_wT<<<(NC * 256 + 255) / 256, 256, 0, stream>>>(W1, wT1, 256);
  k_wT<<<(NC * CC + 255) / 256, 256, 0, stream>>>(W2, wT2, CC);

  // layer 1
  k_gemm_mfma_att<256><<<gB, 256, 0, stream>>>(xh, wT1, as1, ad1, xw, asrc, adst, Nn);
  k_aggregate<true, _Float16><<<aB, 256, 0, stream>>>(xw, asrc, adst, rowptr, deg,
                                                      csr_src, b1, h1h, Nn);

  // layer 2
  k_gemm_mfma_att<64><<<gB, 256, 0, stream>>>(h1h, wT2, as2, ad2, xw, asrc, adst, Nn);
  k_aggregate<false, float><<<aB, 256, 0, stream>>>(xw, asrc, adst, rowptr, deg,
                                                    csr_src, b2, out_h, Nn);

  // final linear
  k_logit<<<lB, 256, 0, stream>>>(out_h, Wl, bl, out_logit, Nn);
}